// Round 1
// baseline (775.376 us; speedup 1.0000x reference)
//
#include <hip/hip_runtime.h>
#include <hip/hip_bf16.h>

#define BATCH 8
#define CH    64
#define HH    112
#define WW    112
#define HW    (HH * WW)          // 12544
#define NP    (BATCH * HW)       // 100352 pixels
#define TAPS  25
#define MIDC  256
#define KW    5

// ---------------------------------------------------------------------------
// Kernel A: fold conv2 (1x1, 256->25) into conv1 weights.
//   weff[c][tap][o] = sum_mid w2[o][mid] * w1[mid][c][tap]   (o contiguous)
//   beff[o]         = b2[o] + sum_mid w2[o][mid] * b1[mid]
// ---------------------------------------------------------------------------
__global__ __launch_bounds__(256) void weff_kernel(
    const float* __restrict__ w1, const float* __restrict__ b1,
    const float* __restrict__ w2, const float* __restrict__ b2,
    float* __restrict__ weff, float* __restrict__ beff) {
  int t = blockIdx.x * 256 + threadIdx.x;
  if (t >= CH * TAPS * TAPS) return;
  int o   = t % TAPS;
  int tap = (t / TAPS) % TAPS;
  int c   = t / (TAPS * TAPS);
  float acc = 0.f;
  const float* w2o = w2 + o * MIDC;
  const float* w1p = w1 + c * TAPS + tap;
  #pragma unroll 8
  for (int mid = 0; mid < MIDC; ++mid)
    acc += w2o[mid] * w1p[mid * (CH * TAPS)];
  weff[(c * TAPS + tap) * TAPS + o] = acc;
  if (t < TAPS) {
    float b = b2[t];
    for (int mid = 0; mid < MIDC; ++mid) b += w2[t * MIDC + mid] * b1[mid];
    beff[t] = b;
  }
}

// ---------------------------------------------------------------------------
// Kernel B: fused  logits -> softmax -> weighted 5x5 dilated gather.
// One thread per output pixel (b,h,w); 25 logits live in registers.
// ---------------------------------------------------------------------------
__global__ __launch_bounds__(256) void picanet_main(
    const float* __restrict__ x, const float* __restrict__ weff,
    const float* __restrict__ beff, float* __restrict__ out) {
  int p = blockIdx.x * 256 + threadIdx.x;
  if (p >= NP) return;
  int w    = p % WW;
  int rest = p / WW;
  int h    = rest % HH;
  int b    = rest / HH;

  // Per-tap source offsets + validity masks (dilation 2, pad 4).
  int   off[TAPS];
  float mask[TAPS];
  #pragma unroll
  for (int i = 0; i < KW; ++i) {
    int yy = h + 2 * i - 4;
    #pragma unroll
    for (int j = 0; j < KW; ++j) {
      int xx = w + 2 * j - 4;
      bool ok = (yy >= 0) & (yy < HH) & (xx >= 0) & (xx < WW);
      off[i * KW + j]  = ok ? (yy * WW + xx) : 0;
      mask[i * KW + j] = ok ? 1.f : 0.f;
    }
  }

  // Logits: s[o] = beff[o] + sum_c sum_tap x[c,tap] * weff[c][tap][o]
  float s[TAPS];
  #pragma unroll
  for (int o = 0; o < TAPS; ++o) s[o] = beff[o];

  const float* xb = x + (size_t)b * CH * HW;
  for (int c = 0; c < CH; ++c) {
    const float* xc = xb + c * HW;
    const float* wc = weff + c * TAPS * TAPS;
    #pragma unroll
    for (int tap = 0; tap < TAPS; ++tap) {
      float xv = xc[off[tap]] * mask[tap];
      const float* wt = wc + tap * TAPS;   // wave-uniform -> scalar loads
      #pragma unroll
      for (int o = 0; o < TAPS; ++o) s[o] += xv * wt[o];
    }
  }

  // Softmax over the 25 taps (all taps participate, matching reference).
  float m = s[0];
  #pragma unroll
  for (int o = 1; o < TAPS; ++o) m = fmaxf(m, s[o]);
  float sum = 0.f;
  #pragma unroll
  for (int o = 0; o < TAPS; ++o) { s[o] = __expf(s[o] - m); sum += s[o]; }
  float inv = 1.f / sum;
  // Fold validity mask into the attention weights so the apply loop needs no
  // per-load masking (invalid taps load a garbage in-bounds value * 0).
  #pragma unroll
  for (int o = 0; o < TAPS; ++o) s[o] *= inv * mask[o];

  // Apply: out[b,c,h,w] = sum_tap s[tap] * x[b,c,tap(h,w)]
  float* ob = out + (size_t)b * CH * HW + h * WW + w;
  for (int c = 0; c < CH; ++c) {
    const float* xc = xb + c * HW;
    float acc = 0.f;
    #pragma unroll
    for (int tap = 0; tap < TAPS; ++tap) acc += s[tap] * xc[off[tap]];
    ob[c * HW] = acc;
  }
}

extern "C" void kernel_launch(void* const* d_in, const int* in_sizes, int n_in,
                              void* d_out, int out_size, void* d_ws, size_t ws_size,
                              hipStream_t stream) {
  const float* x  = (const float*)d_in[0];
  const float* w1 = (const float*)d_in[1];
  const float* b1 = (const float*)d_in[2];
  const float* w2 = (const float*)d_in[3];
  const float* b2 = (const float*)d_in[4];
  float* out  = (float*)d_out;
  float* weff = (float*)d_ws;                       // 40000 floats
  float* beff = weff + CH * TAPS * TAPS;            // 25 floats

  int nA = CH * TAPS * TAPS;                        // 40000
  weff_kernel<<<(nA + 255) / 256, 256, 0, stream>>>(w1, b1, w2, b2, weff, beff);
  picanet_main<<<(NP + 255) / 256, 256, 0, stream>>>(x, weff, beff, out);
}

// Round 2
// 276.736 us; speedup vs baseline: 2.8019x; 2.8019x over previous
//
#include <hip/hip_runtime.h>
#include <hip/hip_bf16.h>

#define BATCH 8
#define CH    64
#define HH    112
#define WW    112
#define HW    (HH * WW)          // 12544
#define NP    (BATCH * HW)       // 100352 pixels
#define TAPS  25
#define MIDC  256
#define PIX   64                 // pixels per block (= 1 wave-width group)
#define CPW   16                 // channels per wave (4 waves * 16 = 64)

// ---------------------------------------------------------------------------
// Kernel A: fold conv2 (1x1, 256->25) into conv1 weights.
//   weff[c][tap][o] = sum_mid w2[o][mid] * w1[mid][c][tap]
//   beff[o]         = b2[o] + sum_mid w2[o][mid] * b1[mid]
// One block per c; w1[:,c,:] staged in LDS to fix the strided access.
// ---------------------------------------------------------------------------
__global__ __launch_bounds__(256) void weff_kernel(
    const float* __restrict__ w1, const float* __restrict__ b1,
    const float* __restrict__ w2, const float* __restrict__ b2,
    float* __restrict__ weff, float* __restrict__ beff) {
  const int c = blockIdx.x;
  __shared__ float sw1[MIDC * TAPS];          // 25.6 KB
  for (int e = threadIdx.x; e < MIDC * TAPS; e += 256) {
    int mid = e / TAPS, tap = e % TAPS;
    sw1[e] = w1[(mid * CH + c) * TAPS + tap];
  }
  __syncthreads();
  // e = o*25 + tap so adjacent lanes share o (w2 row broadcast-loads).
  for (int e = threadIdx.x; e < TAPS * TAPS; e += 256) {
    int o = e / TAPS, tap = e % TAPS;
    const float* w2o = w2 + o * MIDC;
    float acc = 0.f;
    #pragma unroll 8
    for (int mid = 0; mid < MIDC; ++mid)
      acc += sw1[mid * TAPS + tap] * w2o[mid];
    weff[(c * TAPS + tap) * TAPS + o] = acc;
  }
  if (c == 0 && threadIdx.x < TAPS) {
    int o = threadIdx.x;
    float b = b2[o];
    for (int mid = 0; mid < MIDC; ++mid) b += w2[o * MIDC + mid] * b1[mid];
    beff[o] = b;
  }
}

// ---------------------------------------------------------------------------
// Kernel B: fused logits -> cross-wave reduce -> softmax -> weighted gather.
// Block = 256 threads = 4 waves. 64 pixels/block (lane = pixel).
// Wave w owns channels [16w, 16w+16); partial logits reduced via LDS.
// Grid = NP/64 = 1568 blocks -> ~6 blocks/CU, 24 waves/CU.
// ---------------------------------------------------------------------------
__global__ __launch_bounds__(256) void picanet_main(
    const float* __restrict__ x, const float* __restrict__ weff,
    const float* __restrict__ beff, float* __restrict__ out) {
  __shared__ float red[4 * PIX * TAPS];       // 25.6 KB -> 6 blocks/CU by LDS

  const int lane = threadIdx.x & 63;
  const int wave = threadIdx.x >> 6;
  // Force wave-uniformity so weight addresses stay scalar (s_load path).
  const int c0 = __builtin_amdgcn_readfirstlane(wave * CPW);

  const int p  = blockIdx.x * PIX + lane;     // NP % 64 == 0, no tail
  const int b  = p / HW;
  const int hw = p % HW;
  const int h  = hw / WW;
  const int w  = hw % WW;

  const float* xb = x + (size_t)b * CH * HW + (size_t)c0 * HW;
  const float* wc = weff + (size_t)c0 * TAPS * TAPS;

  // ---- Phase 1: partial logits over this wave's 16 channels ----
  float s[TAPS];
  #pragma unroll
  for (int o = 0; o < TAPS; ++o) s[o] = 0.f;

  #pragma unroll 1
  for (int tap = 0; tap < TAPS; ++tap) {
    int i = tap / 5, j = tap % 5;
    int yy = h + 2 * i - 4;
    int xx = w + 2 * j - 4;
    bool ok = (yy >= 0) & (yy < HH) & (xx >= 0) & (xx < WW);
    int   offt = ok ? yy * WW + xx : 0;
    float mk   = ok ? 1.f : 0.f;
    const float* wt = wc + tap * TAPS;
    #pragma unroll
    for (int c = 0; c < CPW; ++c) {
      float xv = xb[(size_t)c * HW + offt] * mk;
      const float* wp = wt + c * (TAPS * TAPS);   // uniform -> scalar loads
      #pragma unroll
      for (int o = 0; o < TAPS; ++o) s[o] = fmaf(xv, wp[o], s[o]);
    }
  }

  #pragma unroll
  for (int o = 0; o < TAPS; ++o) red[(wave * PIX + lane) * TAPS + o] = s[o];
  __syncthreads();

  // ---- Softmax (wave 0 handles all 64 pixels of the block) ----
  if (wave == 0) {
    float t[TAPS];
    #pragma unroll
    for (int o = 0; o < TAPS; ++o)
      t[o] = red[lane * TAPS + o] + red[(PIX + lane) * TAPS + o] +
             red[(2 * PIX + lane) * TAPS + o] + red[(3 * PIX + lane) * TAPS + o] +
             beff[o];
    float m = t[0];
    #pragma unroll
    for (int o = 1; o < TAPS; ++o) m = fmaxf(m, t[o]);
    float sum = 0.f;
    #pragma unroll
    for (int o = 0; o < TAPS; ++o) { t[o] = __expf(t[o] - m); sum += t[o]; }
    float inv = 1.f / sum;
    // Fold tap-validity mask into the final weights (denominator keeps all 25,
    // matching the reference softmax over all output channels).
    #pragma unroll
    for (int o = 0; o < TAPS; ++o) {
      int i = o / 5, j = o % 5;
      int yy = h + 2 * i - 4;
      int xx = w + 2 * j - 4;
      bool ok = (yy >= 0) & (yy < HH) & (xx >= 0) & (xx < WW);
      red[lane * TAPS + o] = ok ? t[o] * inv : 0.f;
    }
  }
  __syncthreads();

  // ---- Phase 2: out[b,c,h,w] = sum_tap sfin[tap] * x[b,c,tap(h,w)] ----
  float acc[CPW];
  #pragma unroll
  for (int c = 0; c < CPW; ++c) acc[c] = 0.f;

  #pragma unroll 1
  for (int tap = 0; tap < TAPS; ++tap) {
    int i = tap / 5, j = tap % 5;
    int yy = h + 2 * i - 4;
    int xx = w + 2 * j - 4;
    bool ok = (yy >= 0) & (yy < HH) & (xx >= 0) & (xx < WW);
    int offt = ok ? yy * WW + xx : 0;      // invalid taps have sfin == 0
    float sv = red[lane * TAPS + tap];     // dynamic index stays in LDS
    #pragma unroll
    for (int c = 0; c < CPW; ++c)
      acc[c] = fmaf(sv, xb[(size_t)c * HW + offt], acc[c]);
  }

  float* ob = out + (size_t)b * CH * HW + (size_t)c0 * HW + hw;
  #pragma unroll
  for (int c = 0; c < CPW; ++c) ob[c * HW] = acc[c];
}

extern "C" void kernel_launch(void* const* d_in, const int* in_sizes, int n_in,
                              void* d_out, int out_size, void* d_ws, size_t ws_size,
                              hipStream_t stream) {
  const float* x  = (const float*)d_in[0];
  const float* w1 = (const float*)d_in[1];
  const float* b1 = (const float*)d_in[2];
  const float* w2 = (const float*)d_in[3];
  const float* b2 = (const float*)d_in[4];
  float* out  = (float*)d_out;
  float* weff = (float*)d_ws;                       // 40000 floats
  float* beff = weff + CH * TAPS * TAPS;            // 25 floats

  weff_kernel<<<CH, 256, 0, stream>>>(w1, b1, w2, b2, weff, beff);
  picanet_main<<<NP / PIX, 256, 0, stream>>>(x, weff, beff, out);
}